// Round 3
// baseline (17171.783 us; speedup 1.0000x reference)
//
#include <hip/hip_runtime.h>
#include <hip/hip_bf16.h>

// RecurrentAE on MI355X — round 3.
//  - Fence-free step sync: h reads/writes are relaxed AGENT-scope atomics (bypass L1/L2,
//    coherent at LLC), so no buffer_wbl2 / buffer_inv per step at all.
//  - Two-level relaxed barrier; encoder overlaps next-step x-GEMM in the arrive->wait window.
//  - x / weights stay L2-cached across all steps (no more per-step invalidation).

#define B_ 128
#define S_ 512
#define F_ 128
#define L_ 1024
#define U_ 8            // units per WG
#define NWG 128         // persistent grid

typedef __bf16 bf16x8 __attribute__((ext_vector_type(8)));
typedef float  f32x4  __attribute__((ext_vector_type(4)));
typedef int    i32x4  __attribute__((ext_vector_type(4)));
typedef unsigned long long u64;

union a16 { u64 q[2]; bf16x8 v; };
union pk2 { unsigned u; __bf16 h[2]; };

// ---------------- workspace layout (bytes) ----------------
#define O_H0   0                          // bf16 [128][1024]  = 262144
#define O_H1   (256*1024)                 // bf16 [128][1024]
#define O_H32  (512*1024)                 // f32  [128][1024]  = 524288
#define O_CTR  (1024*1024)                // barrier counters (enc base +0, dec base +512 uints)
#define O_ZERO_END (1024*1024 + 4096)
#define O_XB   (1024*1024 + 4096)         // bf16 [128][512][128] = 16777216
#define O_WEH  (O_XB  + 16777216)         // bf16 [128][32][1024] = 8388608
#define O_WEX  (O_WEH + 8388608)          // bf16 [128][32][128]  = 1048576
#define O_BE   (O_WEX + 1048576)          // f32  [128][32]       = 16384
#define O_WD   (O_BE  + 16384)            // bf16 [128][48][1024] = 12582912
#define O_BD   (O_WD  + 12582912)         // f32  [128][48]       = 24576
#define O_WC   (O_BD  + 24576)            // bf16 [3072][1024]    = 6291456
// total ~45.2 MB

// ---------------- prep kernels ----------------

__global__ void k_xcvt(const float* __restrict__ x, __bf16* __restrict__ xb, int n) {
    int i = blockIdx.x * 256 + threadIdx.x;
    int stride = gridDim.x * 256;
    for (; i < n; i += stride) xb[i] = (__bf16)x[i];
}

// encoder pack: 32 cols/WG, 4 per unit {r, z, n_i, n_h}
__global__ void k_pack_enc(const float* __restrict__ Wih, const float* __restrict__ Whh,
                           const float* __restrict__ bih, const float* __restrict__ bhh,
                           __bf16* __restrict__ Weh, __bf16* __restrict__ Wex,
                           float* __restrict__ be) {
    int g = blockIdx.x, tid = threadIdx.x;
    for (int i = tid; i < 32 * 1024; i += 256) {
        int c = i >> 10, k = i & 1023;
        int u = g * U_ + (c >> 2), gate = c & 3;
        float v = 0.f;
        if (gate == 0)      v = Whh[(size_t)u * 1024 + k];
        else if (gate == 1) v = Whh[(size_t)(1024 + u) * 1024 + k];
        else if (gate == 3) v = Whh[(size_t)(2048 + u) * 1024 + k];
        Weh[((size_t)g * 32 + c) * 1024 + k] = (__bf16)v;
    }
    for (int i = tid; i < 32 * 128; i += 256) {
        int c = i >> 7, k = i & 127;
        int u = g * U_ + (c >> 2), gate = c & 3;
        float v = 0.f;
        if (gate == 0)      v = Wih[(size_t)u * 128 + k];
        else if (gate == 1) v = Wih[(size_t)(1024 + u) * 128 + k];
        else if (gate == 2) v = Wih[(size_t)(2048 + u) * 128 + k];
        Wex[((size_t)g * 32 + c) * 128 + k] = (__bf16)v;
    }
    if (tid < 32) {
        int c = tid, u = g * U_ + (c >> 2), gate = c & 3;
        float v;
        if (gate == 0)      v = bih[u] + bhh[u];
        else if (gate == 1) v = bih[1024 + u] + bhh[1024 + u];
        else if (gate == 2) v = bih[2048 + u];
        else                v = bhh[2048 + u];
        be[g * 32 + c] = v;
    }
}

// W_comb = W_ih_d @ W_out  (bf16 out; final Wd is bf16 anyway)
__global__ void k_wcomb(const float* __restrict__ Wihd, const float* __restrict__ Wout,
                        __bf16* __restrict__ Wc) {
    __shared__ float a[8][128];
    int r0 = blockIdx.x * 8, tid = threadIdx.x;
    for (int i = tid; i < 8 * 128; i += 256)
        a[i >> 7][i & 127] = Wihd[(size_t)(r0 + (i >> 7)) * 128 + (i & 127)];
    __syncthreads();
    for (int j = tid; j < 1024; j += 256) {
        float acc[8] = {0, 0, 0, 0, 0, 0, 0, 0};
        for (int f = 0; f < 128; ++f) {
            float w = Wout[(size_t)f * 1024 + j];
#pragma unroll
            for (int r = 0; r < 8; ++r) acc[r] += a[r][f] * w;
        }
        for (int r = 0; r < 8; ++r) Wc[(size_t)(r0 + r) * 1024 + j] = (__bf16)acc[r];
    }
}

// decoder pack: 48 cols/WG — 32 gate cols {r:Whh+Wc, z:Whh+Wc, n_i:Wc, n_h:Whh},
// cols 32..39 = W_out rows g*8..g*8+7 (WGs 0..15), 40..47 zero.
__global__ void k_pack_dec(const float* __restrict__ Whhd, const __bf16* __restrict__ Wc,
                           const float* __restrict__ Wout, const float* __restrict__ Wihd,
                           const float* __restrict__ bihd, const float* __restrict__ bhhd,
                           const float* __restrict__ bout,
                           __bf16* __restrict__ Wd, float* __restrict__ bd) {
    int g = blockIdx.x, tid = threadIdx.x;
    for (int i = tid; i < 48 * 1024; i += 256) {
        int c = i >> 10, k = i & 1023;
        float v = 0.f;
        if (c < 32) {
            int u = g * U_ + (c >> 2), gate = c & 3;
            if (gate == 0)      v = Whhd[(size_t)u * 1024 + k] + (float)Wc[(size_t)u * 1024 + k];
            else if (gate == 1) v = Whhd[(size_t)(1024 + u) * 1024 + k] + (float)Wc[(size_t)(1024 + u) * 1024 + k];
            else if (gate == 2) v = (float)Wc[(size_t)(2048 + u) * 1024 + k];
            else                v = Whhd[(size_t)(2048 + u) * 1024 + k];
        } else if (c < 40 && g < 16) {
            v = Wout[(size_t)(g * 8 + (c - 32)) * 1024 + k];
        }
        Wd[((size_t)g * 48 + c) * 1024 + k] = (__bf16)v;
    }
    if (tid < 48) {
        int c = tid;
        float v = 0.f;
        if (c < 32) {
            int u = g * U_ + (c >> 2), gate = c & 3;
            int row = (gate == 0) ? u : (gate == 1) ? (1024 + u) : (2048 + u);
            if (gate <= 1) {
                float d = 0.f;
                for (int f = 0; f < 128; ++f) d += Wihd[(size_t)row * 128 + f] * bout[f];
                v = d + bihd[row] + bhhd[row];
            } else if (gate == 2) {
                float d = 0.f;
                for (int f = 0; f < 128; ++f) d += Wihd[(size_t)row * 128 + f] * bout[f];
                v = d + bihd[row];
            } else {
                v = bhhd[row];
            }
        } else if (c < 40 && g < 16) {
            v = bout[g * 8 + (c - 32)];
        }
        bd[g * 48 + c] = v;
    }
}

// ---------------- fence-free two-level barrier pieces ----------------
// h stores are agent-scope write-through; __syncthreads' vmcnt(0) drain puts them
// at the LLC before the arrive atomic. h reads are agent-scope atomic loads that
// bypass L1/L2 -> always fresh. No buffer_wbl2 / buffer_inv anywhere.
__device__ __forceinline__ void bar_arrive(unsigned* base, int g, unsigned step1) {
    if (threadIdx.x == 0) {
        unsigned* sub  = base + (g & 7) * 32;
        unsigned old = __hip_atomic_fetch_add(sub, 1u, __ATOMIC_RELAXED, __HIP_MEMORY_SCOPE_AGENT);
        if (old == step1 * (NWG / 8) - 1)
            __hip_atomic_fetch_add(base + 256, 1u, __ATOMIC_RELAXED, __HIP_MEMORY_SCOPE_AGENT);
    }
}
__device__ __forceinline__ void bar_wait(unsigned* base, unsigned step1) {
    if (threadIdx.x == 0) {
        while (__hip_atomic_load(base + 256, __ATOMIC_RELAXED, __HIP_MEMORY_SCOPE_AGENT) < step1 * 8u)
            __builtin_amdgcn_s_sleep(1);
    }
    __syncthreads();
}

__device__ __forceinline__ bf16x8 load_h16(const u64* p) {
    a16 t;
    t.q[0] = __hip_atomic_load(p,     __ATOMIC_RELAXED, __HIP_MEMORY_SCOPE_AGENT);
    t.q[1] = __hip_atomic_load(p + 1, __ATOMIC_RELAXED, __HIP_MEMORY_SCOPE_AGENT);
    return t.v;
}

// ---------------- encoder ----------------
__global__ __launch_bounds__(512) void k_enc(
    const __bf16* __restrict__ xb, const __bf16* __restrict__ Weh,
    const __bf16* __restrict__ Wex, const float* __restrict__ be,
    __bf16* __restrict__ h0, __bf16* __restrict__ h1,
    float* __restrict__ h32, unsigned* __restrict__ ctr) {
    __shared__ __align__(16) __bf16 sWh[32][1032];
    __shared__ __align__(16) __bf16 sWx[32][136];
    __shared__ float sB[32];
    __shared__ __align__(16) float sG[128][36];
    const int g = blockIdx.x, tid = threadIdx.x;
    const int lane = tid & 63, wave = tid >> 6;

    for (int i = tid; i < 32 * 128; i += 512) {
        int c = i >> 7, k8 = i & 127;
        *(i32x4*)&sWh[c][k8 * 8] = *(const i32x4*)(Weh + ((size_t)g * 32 + c) * 1024 + k8 * 8);
    }
    for (int i = tid; i < 32 * 16; i += 512) {
        int c = i >> 4, k8 = i & 15;
        *(i32x4*)&sWx[c][k8 * 8] = *(const i32x4*)(Wex + ((size_t)g * 32 + c) * 128 + k8 * 8);
    }
    if (tid < 32) sB[tid] = be[g * 32 + tid];
    __syncthreads();

    const int m0 = wave * 16;                  // 8 waves cover M=128
    const int rowA = m0 + (lane & 15);
    const int kq = (lane >> 4) * 8;
    const int bcol = lane & 15;
    const int erow = tid >> 2, pair = tid & 3;
    const int hidx2 = erow * 512 + g * 4 + pair;   // uint index (2 bf16 per uint)
    float ha = 0.f, hb = 0.f;

    // x-part of step 0
    f32x4 acc0 = {0.f, 0.f, 0.f, 0.f};
    f32x4 acc1 = {0.f, 0.f, 0.f, 0.f};
    {
        const __bf16* xr = xb + (size_t)rowA * 65536;
#pragma unroll
        for (int kt = 0; kt < 4; ++kt) {
            bf16x8 a = *(const bf16x8*)(xr + kt * 32 + kq);
            acc0 = __builtin_amdgcn_mfma_f32_16x16x32_bf16(a, *(const bf16x8*)(&sWx[bcol][kt * 32 + kq]), acc0, 0, 0, 0);
            acc1 = __builtin_amdgcn_mfma_f32_16x16x32_bf16(a, *(const bf16x8*)(&sWx[16 + bcol][kt * 32 + kq]), acc1, 0, 0, 0);
        }
    }

    for (int s = 0; s < 512; ++s) {
        const __bf16* hcur = (s & 1) ? h1 : h0;
        __bf16* hnxt = (s & 1) ? h0 : h1;
        // h part (K=1024), coherent LLC loads; A-frag reused for both N-tiles
        const u64* hq = (const u64*)(hcur + (size_t)rowA * 1024) + (lane >> 4) * 2;
#pragma unroll
        for (int kt = 0; kt < 32; ++kt) {
            bf16x8 a = load_h16(hq + kt * 8);
            acc0 = __builtin_amdgcn_mfma_f32_16x16x32_bf16(a, *(const bf16x8*)(&sWh[bcol][kt * 32 + kq]), acc0, 0, 0, 0);
            acc1 = __builtin_amdgcn_mfma_f32_16x16x32_bf16(a, *(const bf16x8*)(&sWh[16 + bcol][kt * 32 + kq]), acc1, 0, 0, 0);
        }
        {   // C frag: col=lane&15, row=(lane>>4)*4+reg
            int r0 = m0 + ((lane >> 4) << 2);
#pragma unroll
            for (int i = 0; i < 4; ++i) {
                sG[r0 + i][bcol] = acc0[i];
                sG[r0 + i][16 + bcol] = acc1[i];
            }
        }
        __syncthreads();
        {
            f32x4 g0 = *(const f32x4*)&sG[erow][pair * 8];
            f32x4 g1 = *(const f32x4*)&sG[erow][pair * 8 + 4];
            int c0 = pair * 8;
            float r = 1.f / (1.f + __expf(-(g0[0] + sB[c0 + 0])));
            float z = 1.f / (1.f + __expf(-(g0[1] + sB[c0 + 1])));
            float n = tanhf(g0[2] + sB[c0 + 2] + r * (g0[3] + sB[c0 + 3]));
            ha = (1.f - z) * n + z * ha;
            r = 1.f / (1.f + __expf(-(g1[0] + sB[c0 + 4])));
            z = 1.f / (1.f + __expf(-(g1[1] + sB[c0 + 5])));
            n = tanhf(g1[2] + sB[c0 + 6] + r * (g1[3] + sB[c0 + 7]));
            hb = (1.f - z) * n + z * hb;
            pk2 p; p.h[0] = (__bf16)ha; p.h[1] = (__bf16)hb;
            __hip_atomic_store((unsigned*)hnxt + hidx2, p.u, __ATOMIC_RELAXED, __HIP_MEMORY_SCOPE_AGENT);
            if (s == 511) {
                h32[erow * 1024 + g * 8 + pair * 2]     = ha;
                h32[erow * 1024 + g * 8 + pair * 2 + 1] = hb;
            }
        }
        if (s < 511) {
            __syncthreads();              // drains h stores (vmcnt 0) before arrive
            bar_arrive(ctr, g, (unsigned)(s + 1));
            // overlap: x-part of step s+1 while the grid converges
            acc0 = f32x4{0.f, 0.f, 0.f, 0.f};
            acc1 = f32x4{0.f, 0.f, 0.f, 0.f};
            const __bf16* xr = xb + (size_t)rowA * 65536 + (s + 1) * 128;
#pragma unroll
            for (int kt = 0; kt < 4; ++kt) {
                bf16x8 a = *(const bf16x8*)(xr + kt * 32 + kq);
                acc0 = __builtin_amdgcn_mfma_f32_16x16x32_bf16(a, *(const bf16x8*)(&sWx[bcol][kt * 32 + kq]), acc0, 0, 0, 0);
                acc1 = __builtin_amdgcn_mfma_f32_16x16x32_bf16(a, *(const bf16x8*)(&sWx[16 + bcol][kt * 32 + kq]), acc1, 0, 0, 0);
            }
            bar_wait(ctr, (unsigned)(s + 1));
        }
    }
}

// ---------------- decoder ----------------
__global__ __launch_bounds__(512) void k_dec(
    const __bf16* __restrict__ Wd, const float* __restrict__ bd,
    __bf16* __restrict__ h0, __bf16* __restrict__ h1,
    const float* __restrict__ h32, float* __restrict__ out,
    unsigned* __restrict__ ctr) {
    __shared__ __align__(16) __bf16 sWd[48][1032];
    __shared__ float sB[48];
    __shared__ __align__(16) float sG[128][52];
    const int g = blockIdx.x, tid = threadIdx.x;
    const int lane = tid & 63, wave = tid >> 6;
    const bool has_out = (g < 16);

    for (int i = tid; i < 48 * 128; i += 512) {
        int c = i >> 7, k8 = i & 127;
        *(i32x4*)&sWd[c][k8 * 8] = *(const i32x4*)(Wd + ((size_t)g * 48 + c) * 1024 + k8 * 8);
    }
    if (tid < 48) sB[tid] = bd[g * 48 + tid];
    __syncthreads();

    const int m0 = wave * 16;
    const int rowA = m0 + (lane & 15);
    const int kq = (lane >> 4) * 8;
    const int bcol = lane & 15;
    const int erow = tid >> 2, pair = tid & 3;
    const int hidx2 = erow * 512 + g * 4 + pair;
    float ha = h32[erow * 1024 + g * 8 + pair * 2];
    float hb = h32[erow * 1024 + g * 8 + pair * 2 + 1];

    for (int s = 0; s <= 512; ++s) {
        const __bf16* hcur = (s & 1) ? h1 : h0;
        __bf16* hnxt = (s & 1) ? h0 : h1;
        f32x4 acc0 = {0.f, 0.f, 0.f, 0.f};
        f32x4 acc1 = {0.f, 0.f, 0.f, 0.f};
        f32x4 acc2 = {0.f, 0.f, 0.f, 0.f};
        const u64* hq = (const u64*)(hcur + (size_t)rowA * 1024) + (lane >> 4) * 2;
#pragma unroll
        for (int kt = 0; kt < 32; ++kt) {
            bf16x8 a = load_h16(hq + kt * 8);
            acc0 = __builtin_amdgcn_mfma_f32_16x16x32_bf16(a, *(const bf16x8*)(&sWd[bcol][kt * 32 + kq]), acc0, 0, 0, 0);
            acc1 = __builtin_amdgcn_mfma_f32_16x16x32_bf16(a, *(const bf16x8*)(&sWd[16 + bcol][kt * 32 + kq]), acc1, 0, 0, 0);
            if (has_out)
                acc2 = __builtin_amdgcn_mfma_f32_16x16x32_bf16(a, *(const bf16x8*)(&sWd[32 + bcol][kt * 32 + kq]), acc2, 0, 0, 0);
        }
        int r0 = m0 + ((lane >> 4) << 2);
        if (s < 512) {
#pragma unroll
            for (int i = 0; i < 4; ++i) {
                sG[r0 + i][bcol] = acc0[i];
                sG[r0 + i][16 + bcol] = acc1[i];
            }
        }
        if (has_out) {
#pragma unroll
            for (int i = 0; i < 4; ++i) sG[r0 + i][32 + bcol] = acc2[i];
        }
        __syncthreads();
        // out tile: cols 32..39 = x_s rows (pre-bias); flip to out[:, 512-s, :]
        if (s >= 1 && has_out && tid < 256) {
            int row = tid >> 1, half = tid & 1;
            f32x4 v = *(const f32x4*)&sG[row][32 + half * 4];
            f32x4 bo = *(const f32x4*)&sB[32 + half * 4];
            v = v + bo;
            *(f32x4*)(out + (size_t)row * 65536 + (size_t)(512 - s) * 128 + g * 8 + half * 4) = v;
        }
        if (s < 512) {
            f32x4 g0 = *(const f32x4*)&sG[erow][pair * 8];
            f32x4 g1 = *(const f32x4*)&sG[erow][pair * 8 + 4];
            int c0 = pair * 8;
            float r = 1.f / (1.f + __expf(-(g0[0] + sB[c0 + 0])));
            float z = 1.f / (1.f + __expf(-(g0[1] + sB[c0 + 1])));
            float n = tanhf(g0[2] + sB[c0 + 2] + r * (g0[3] + sB[c0 + 3]));
            ha = (1.f - z) * n + z * ha;
            r = 1.f / (1.f + __expf(-(g1[0] + sB[c0 + 4])));
            z = 1.f / (1.f + __expf(-(g1[1] + sB[c0 + 5])));
            n = tanhf(g1[2] + sB[c0 + 6] + r * (g1[3] + sB[c0 + 7]));
            hb = (1.f - z) * n + z * hb;
            pk2 p; p.h[0] = (__bf16)ha; p.h[1] = (__bf16)hb;
            __hip_atomic_store((unsigned*)hnxt + hidx2, p.u, __ATOMIC_RELAXED, __HIP_MEMORY_SCOPE_AGENT);
            __syncthreads();              // drains h stores before arrive
            bar_arrive(ctr, g, (unsigned)(s + 1));
            bar_wait(ctr, (unsigned)(s + 1));
        }
    }
}

// ---------------- launch ----------------
extern "C" void kernel_launch(void* const* d_in, const int* in_sizes, int n_in,
                              void* d_out, int out_size, void* d_ws, size_t ws_size,
                              hipStream_t stream) {
    (void)in_sizes; (void)n_in; (void)out_size; (void)ws_size;
    const float* x    = (const float*)d_in[0];
    const float* Wihe = (const float*)d_in[1];
    const float* Whhe = (const float*)d_in[2];
    const float* bihe = (const float*)d_in[3];
    const float* bhhe = (const float*)d_in[4];
    const float* Wihd = (const float*)d_in[5];
    const float* Whhd = (const float*)d_in[6];
    const float* bihd = (const float*)d_in[7];
    const float* bhhd = (const float*)d_in[8];
    const float* Wout = (const float*)d_in[9];
    const float* bout = (const float*)d_in[10];

    char* ws = (char*)d_ws;
    __bf16*   h0  = (__bf16*)(ws + O_H0);
    __bf16*   h1  = (__bf16*)(ws + O_H1);
    float*    h32 = (float*)(ws + O_H32);
    unsigned* ctr = (unsigned*)(ws + O_CTR);
    __bf16*   xbf = (__bf16*)(ws + O_XB);
    __bf16*   Weh = (__bf16*)(ws + O_WEH);
    __bf16*   Wex = (__bf16*)(ws + O_WEX);
    float*    be  = (float*)(ws + O_BE);
    __bf16*   Wd  = (__bf16*)(ws + O_WD);
    float*    bd  = (float*)(ws + O_BD);
    __bf16*   Wc  = (__bf16*)(ws + O_WC);

    hipMemsetAsync(ws, 0, O_ZERO_END, stream);   // h0/h1/h32 + barrier counters

    k_xcvt<<<4096, 256, 0, stream>>>(x, xbf, B_ * S_ * F_);
    k_pack_enc<<<NWG, 256, 0, stream>>>(Wihe, Whhe, bihe, bhhe, Weh, Wex, be);
    k_wcomb<<<384, 256, 0, stream>>>(Wihd, Wout, Wc);
    k_pack_dec<<<NWG, 256, 0, stream>>>(Whhd, Wc, Wout, Wihd, bihd, bhhd, bout, Wd, bd);

    k_enc<<<NWG, 512, 0, stream>>>(xbf, Weh, Wex, be, h0, h1, h32, ctr);
    k_dec<<<NWG, 512, 0, stream>>>(Wd, bd, h0, h1, h32, (float*)d_out, ctr + 512);
}

// Round 4
// 10793.554 us; speedup vs baseline: 1.5909x; 1.5909x over previous
//
#include <hip/hip_runtime.h>
#include <hip/hip_bf16.h>

// RecurrentAE on MI355X — round 4.
//  - 128 persistent WGs x 512 thr; weights LDS-resident; 1 step = 1 MFMA GEMM + gate math + grid sync.
//  - h broadcast: write-through agent-atomic stores (L2 never dirty for h) + plain CACHED vector reads.
//  - Per-step coherence: ONE buffer_inv sc0 sc1 per XCD (leader WG, elected via HW_REG_XCC_ID),
//    non-leaders only inv their own L1 (buffer_inv sc0). No release fences at all.
//  - Barrier: 16 relaxed sub-counters -> leaders poll sum -> per-XCD epoch broadcast.
//  - out / h stores write-through atomics so invalidates can never drop dirty data.

#define B_ 128
#define S_ 512
#define F_ 128
#define L_ 1024
#define U_ 8            // units per WG
#define NWG 128         // persistent grid
#define SUBN 16         // barrier sub-counters

typedef __bf16 bf16x8 __attribute__((ext_vector_type(8)));
typedef float  f32x4  __attribute__((ext_vector_type(4)));
typedef int    i32x4  __attribute__((ext_vector_type(4)));
typedef unsigned long long u64;

union pk2 { unsigned u; __bf16 h[2]; };
union f2q { f32x4 v; u64 q[2]; };

// ---------------- workspace layout (bytes) ----------------
#define O_H0   0                          // bf16 [128][1024]  = 262144
#define O_H1   (256*1024)                 // bf16 [128][1024]
#define O_H32  (512*1024)                 // f32  [128][1024]  = 524288
#define O_CTR  (1024*1024)                // sync block: enc @ +0, dec @ +4096 (1024 u32 each)
#define O_ZERO_END (1024*1024 + 8192)
#define O_XB   (1024*1024 + 8192)         // bf16 [128][512][128] = 16777216
#define O_WEH  (O_XB  + 16777216)         // bf16 [128][32][1024] = 8388608
#define O_WEX  (O_WEH + 8388608)          // bf16 [128][32][128]  = 1048576
#define O_BE   (O_WEX + 1048576)          // f32  [128][32]       = 16384
#define O_WD   (O_BE  + 16384)            // bf16 [128][48][1024] = 12582912
#define O_BD   (O_WD  + 12582912)         // f32  [128][48]       = 24576
#define O_WC   (O_BD  + 24576)            // bf16 [3072][1024]    = 6291456
// total ~45.2 MB

// ---------------- prep kernels ----------------

__global__ void k_xcvt(const float* __restrict__ x, __bf16* __restrict__ xb, int n) {
    int i = blockIdx.x * 256 + threadIdx.x;
    int stride = gridDim.x * 256;
    for (; i < n; i += stride) xb[i] = (__bf16)x[i];
}

// encoder pack: 32 cols/WG, 4 per unit {r, z, n_i, n_h}
__global__ void k_pack_enc(const float* __restrict__ Wih, const float* __restrict__ Whh,
                           const float* __restrict__ bih, const float* __restrict__ bhh,
                           __bf16* __restrict__ Weh, __bf16* __restrict__ Wex,
                           float* __restrict__ be) {
    int g = blockIdx.x, tid = threadIdx.x;
    for (int i = tid; i < 32 * 1024; i += 256) {
        int c = i >> 10, k = i & 1023;
        int u = g * U_ + (c >> 2), gate = c & 3;
        float v = 0.f;
        if (gate == 0)      v = Whh[(size_t)u * 1024 + k];
        else if (gate == 1) v = Whh[(size_t)(1024 + u) * 1024 + k];
        else if (gate == 3) v = Whh[(size_t)(2048 + u) * 1024 + k];
        Weh[((size_t)g * 32 + c) * 1024 + k] = (__bf16)v;
    }
    for (int i = tid; i < 32 * 128; i += 256) {
        int c = i >> 7, k = i & 127;
        int u = g * U_ + (c >> 2), gate = c & 3;
        float v = 0.f;
        if (gate == 0)      v = Wih[(size_t)u * 128 + k];
        else if (gate == 1) v = Wih[(size_t)(1024 + u) * 128 + k];
        else if (gate == 2) v = Wih[(size_t)(2048 + u) * 128 + k];
        Wex[((size_t)g * 32 + c) * 128 + k] = (__bf16)v;
    }
    if (tid < 32) {
        int c = tid, u = g * U_ + (c >> 2), gate = c & 3;
        float v;
        if (gate == 0)      v = bih[u] + bhh[u];
        else if (gate == 1) v = bih[1024 + u] + bhh[1024 + u];
        else if (gate == 2) v = bih[2048 + u];
        else                v = bhh[2048 + u];
        be[g * 32 + c] = v;
    }
}

// W_comb = W_ih_d @ W_out  (bf16 out; final Wd is bf16 anyway)
__global__ void k_wcomb(const float* __restrict__ Wihd, const float* __restrict__ Wout,
                        __bf16* __restrict__ Wc) {
    __shared__ float a[8][128];
    int r0 = blockIdx.x * 8, tid = threadIdx.x;
    for (int i = tid; i < 8 * 128; i += 256)
        a[i >> 7][i & 127] = Wihd[(size_t)(r0 + (i >> 7)) * 128 + (i & 127)];
    __syncthreads();
    for (int j = tid; j < 1024; j += 256) {
        float acc[8] = {0, 0, 0, 0, 0, 0, 0, 0};
        for (int f = 0; f < 128; ++f) {
            float w = Wout[(size_t)f * 1024 + j];
#pragma unroll
            for (int r = 0; r < 8; ++r) acc[r] += a[r][f] * w;
        }
        for (int r = 0; r < 8; ++r) Wc[(size_t)(r0 + r) * 1024 + j] = (__bf16)acc[r];
    }
}

// decoder pack: 48 cols/WG — 32 gate cols {r:Whh+Wc, z:Whh+Wc, n_i:Wc, n_h:Whh},
// cols 32..39 = W_out rows g*8..g*8+7 (WGs 0..15), 40..47 zero.
__global__ void k_pack_dec(const float* __restrict__ Whhd, const __bf16* __restrict__ Wc,
                           const float* __restrict__ Wout, const float* __restrict__ Wihd,
                           const float* __restrict__ bihd, const float* __restrict__ bhhd,
                           const float* __restrict__ bout,
                           __bf16* __restrict__ Wd, float* __restrict__ bd) {
    int g = blockIdx.x, tid = threadIdx.x;
    for (int i = tid; i < 48 * 1024; i += 256) {
        int c = i >> 10, k = i & 1023;
        float v = 0.f;
        if (c < 32) {
            int u = g * U_ + (c >> 2), gate = c & 3;
            if (gate == 0)      v = Whhd[(size_t)u * 1024 + k] + (float)Wc[(size_t)u * 1024 + k];
            else if (gate == 1) v = Whhd[(size_t)(1024 + u) * 1024 + k] + (float)Wc[(size_t)(1024 + u) * 1024 + k];
            else if (gate == 2) v = (float)Wc[(size_t)(2048 + u) * 1024 + k];
            else                v = Whhd[(size_t)(2048 + u) * 1024 + k];
        } else if (c < 40 && g < 16) {
            v = Wout[(size_t)(g * 8 + (c - 32)) * 1024 + k];
        }
        Wd[((size_t)g * 48 + c) * 1024 + k] = (__bf16)v;
    }
    if (tid < 48) {
        int c = tid;
        float v = 0.f;
        if (c < 32) {
            int u = g * U_ + (c >> 2), gate = c & 3;
            int row = (gate == 0) ? u : (gate == 1) ? (1024 + u) : (2048 + u);
            if (gate <= 1) {
                float d = 0.f;
                for (int f = 0; f < 128; ++f) d += Wihd[(size_t)row * 128 + f] * bout[f];
                v = d + bihd[row] + bhhd[row];
            } else if (gate == 2) {
                float d = 0.f;
                for (int f = 0; f < 128; ++f) d += Wihd[(size_t)row * 128 + f] * bout[f];
                v = d + bihd[row];
            } else {
                v = bhhd[row];
            }
        } else if (c < 40 && g < 16) {
            v = bout[g * 8 + (c - 32)];
        }
        bd[g * 48 + c] = v;
    }
}

// ---------------- sync block layout (u32 indices within a kernel's 4096B region) ----
//   subs : [j*32]        j<16   (arrival counters, 128B apart)
//   epoch: [512 + x*32]  x<8    (per-XCD step epoch, written by leader)
//   claim: [768 + x*32]  x<8    (leader election)

__device__ __forceinline__ void bar_arrive(unsigned* base, int g) {
    if (threadIdx.x == 0)
        __hip_atomic_fetch_add(base + (g & (SUBN - 1)) * 32, 1u,
                               __ATOMIC_RELAXED, __HIP_MEMORY_SCOPE_AGENT);
}

__device__ __forceinline__ void bar_wait(unsigned* base, int xcd, bool lead, unsigned step1) {
    if (threadIdx.x == 0) {
        if (lead) {
            unsigned tgt = step1 * NWG;
            for (;;) {
                unsigned sum = 0;
#pragma unroll
                for (int j = 0; j < SUBN; ++j)
                    sum += __hip_atomic_load(base + j * 32, __ATOMIC_RELAXED, __HIP_MEMORY_SCOPE_AGENT);
                if (sum >= tgt) break;
                __builtin_amdgcn_s_sleep(1);
            }
            // one L2(+L1) invalidate per XCD per step; h producers wrote through, so
            // the post-inv refill from LLC is fresh. LLC itself is memory-side coherent.
            asm volatile("buffer_inv sc0 sc1\n\ts_waitcnt vmcnt(0)" ::: "memory");
            __hip_atomic_store(base + 512 + xcd * 32, step1,
                               __ATOMIC_RELAXED, __HIP_MEMORY_SCOPE_AGENT);
        } else {
            while (__hip_atomic_load(base + 512 + xcd * 32,
                                     __ATOMIC_RELAXED, __HIP_MEMORY_SCOPE_AGENT) < step1)
                __builtin_amdgcn_s_sleep(1);
            // own-CU L1 invalidate only (stale h lines from 2 steps ago)
            asm volatile("buffer_inv sc0\n\ts_waitcnt vmcnt(0)" ::: "memory");
        }
    }
    __syncthreads();
}

// thread0-only: physical XCD id + leader election (first claimant per XCD)
__device__ __forceinline__ void elect(unsigned* base, int& xcd, bool& lead) {
    if (threadIdx.x == 0) {
        int x;
        asm volatile("s_getreg_b32 %0, hwreg(HW_REG_XCC_ID)" : "=s"(x));
        xcd = x & 7;
        unsigned old = __hip_atomic_fetch_add(base + 768 + xcd * 32, 1u,
                                              __ATOMIC_RELAXED, __HIP_MEMORY_SCOPE_AGENT);
        lead = (old == 0);
    }
}

// ---------------- encoder ----------------
__global__ __launch_bounds__(512) void k_enc(
    const __bf16* __restrict__ xb, const __bf16* __restrict__ Weh,
    const __bf16* __restrict__ Wex, const float* __restrict__ be,
    __bf16* __restrict__ h0, __bf16* __restrict__ h1,
    float* __restrict__ h32, unsigned* __restrict__ ctr) {
    __shared__ __align__(16) __bf16 sWh[32][1032];
    __shared__ __align__(16) __bf16 sWx[32][136];
    __shared__ float sB[32];
    __shared__ __align__(16) float sG[128][36];
    const int g = blockIdx.x, tid = threadIdx.x;
    const int lane = tid & 63, wave = tid >> 6;

    int xcd = 0; bool lead = false;
    elect(ctr, xcd, lead);

    for (int i = tid; i < 32 * 128; i += 512) {
        int c = i >> 7, k8 = i & 127;
        *(i32x4*)&sWh[c][k8 * 8] = *(const i32x4*)(Weh + ((size_t)g * 32 + c) * 1024 + k8 * 8);
    }
    for (int i = tid; i < 32 * 16; i += 512) {
        int c = i >> 4, k8 = i & 15;
        *(i32x4*)&sWx[c][k8 * 8] = *(const i32x4*)(Wex + ((size_t)g * 32 + c) * 128 + k8 * 8);
    }
    if (tid < 32) sB[tid] = be[g * 32 + tid];
    __syncthreads();

    const int m0 = wave * 16;                  // 8 waves cover M=128
    const int rowA = m0 + (lane & 15);
    const int kq = (lane >> 4) * 8;
    const int bcol = lane & 15;
    const int erow = tid >> 2, pair = tid & 3;
    const int hidx2 = erow * 512 + g * 4 + pair;   // uint index (2 bf16 per uint)
    float ha = 0.f, hb = 0.f;

    // x-part of step 0
    f32x4 acc0 = {0.f, 0.f, 0.f, 0.f};
    f32x4 acc1 = {0.f, 0.f, 0.f, 0.f};
    {
        const __bf16* xr = xb + (size_t)rowA * 65536;
#pragma unroll
        for (int kt = 0; kt < 4; ++kt) {
            bf16x8 a = *(const bf16x8*)(xr + kt * 32 + kq);
            acc0 = __builtin_amdgcn_mfma_f32_16x16x32_bf16(a, *(const bf16x8*)(&sWx[bcol][kt * 32 + kq]), acc0, 0, 0, 0);
            acc1 = __builtin_amdgcn_mfma_f32_16x16x32_bf16(a, *(const bf16x8*)(&sWx[16 + bcol][kt * 32 + kq]), acc1, 0, 0, 0);
        }
    }

    for (int s = 0; s < 512; ++s) {
        const __bf16* hcur = (s & 1) ? h1 : h0;
        __bf16* hnxt = (s & 1) ? h0 : h1;
        // h part (K=1024): plain cached loads (L2 fresh via leader inv, L1 via own inv)
        const __bf16* hr = hcur + (size_t)rowA * 1024;
#pragma unroll 8
        for (int kt = 0; kt < 32; ++kt) {
            bf16x8 a = *(const bf16x8*)(hr + kt * 32 + kq);
            acc0 = __builtin_amdgcn_mfma_f32_16x16x32_bf16(a, *(const bf16x8*)(&sWh[bcol][kt * 32 + kq]), acc0, 0, 0, 0);
            acc1 = __builtin_amdgcn_mfma_f32_16x16x32_bf16(a, *(const bf16x8*)(&sWh[16 + bcol][kt * 32 + kq]), acc1, 0, 0, 0);
        }
        {   // C frag: col=lane&15, row=(lane>>4)*4+reg
            int r0 = m0 + ((lane >> 4) << 2);
#pragma unroll
            for (int i = 0; i < 4; ++i) {
                sG[r0 + i][bcol] = acc0[i];
                sG[r0 + i][16 + bcol] = acc1[i];
            }
        }
        __syncthreads();
        {
            f32x4 g0 = *(const f32x4*)&sG[erow][pair * 8];
            f32x4 g1 = *(const f32x4*)&sG[erow][pair * 8 + 4];
            int c0 = pair * 8;
            float r = 1.f / (1.f + __expf(-(g0[0] + sB[c0 + 0])));
            float z = 1.f / (1.f + __expf(-(g0[1] + sB[c0 + 1])));
            float n = tanhf(g0[2] + sB[c0 + 2] + r * (g0[3] + sB[c0 + 3]));
            ha = (1.f - z) * n + z * ha;
            r = 1.f / (1.f + __expf(-(g1[0] + sB[c0 + 4])));
            z = 1.f / (1.f + __expf(-(g1[1] + sB[c0 + 5])));
            n = tanhf(g1[2] + sB[c0 + 6] + r * (g1[3] + sB[c0 + 7]));
            hb = (1.f - z) * n + z * hb;
            pk2 p; p.h[0] = (__bf16)ha; p.h[1] = (__bf16)hb;
            __hip_atomic_store((unsigned*)hnxt + hidx2, p.u, __ATOMIC_RELAXED, __HIP_MEMORY_SCOPE_AGENT);
            if (s == 511) {
                h32[erow * 1024 + g * 8 + pair * 2]     = ha;
                h32[erow * 1024 + g * 8 + pair * 2 + 1] = hb;
            }
        }
        if (s < 511) {
            __syncthreads();              // drains write-through h stores (vmcnt 0)
            bar_arrive(ctr, g);
            // overlap: x-part of step s+1 (x is read-only — safe to read pre-inv)
            acc0 = f32x4{0.f, 0.f, 0.f, 0.f};
            acc1 = f32x4{0.f, 0.f, 0.f, 0.f};
            const __bf16* xr = xb + (size_t)rowA * 65536 + (s + 1) * 128;
#pragma unroll
            for (int kt = 0; kt < 4; ++kt) {
                bf16x8 a = *(const bf16x8*)(xr + kt * 32 + kq);
                acc0 = __builtin_amdgcn_mfma_f32_16x16x32_bf16(a, *(const bf16x8*)(&sWx[bcol][kt * 32 + kq]), acc0, 0, 0, 0);
                acc1 = __builtin_amdgcn_mfma_f32_16x16x32_bf16(a, *(const bf16x8*)(&sWx[16 + bcol][kt * 32 + kq]), acc1, 0, 0, 0);
            }
            bar_wait(ctr, xcd, lead, (unsigned)(s + 1));
        }
    }
}

// ---------------- decoder ----------------
__global__ __launch_bounds__(512) void k_dec(
    const __bf16* __restrict__ Wd, const float* __restrict__ bd,
    __bf16* __restrict__ h0, __bf16* __restrict__ h1,
    const float* __restrict__ h32, float* __restrict__ out,
    unsigned* __restrict__ ctr) {
    __shared__ __align__(16) __bf16 sWd[48][1032];
    __shared__ float sB[48];
    __shared__ __align__(16) float sG[128][52];
    const int g = blockIdx.x, tid = threadIdx.x;
    const int lane = tid & 63, wave = tid >> 6;
    const bool has_out = (g < 16);

    int xcd = 0; bool lead = false;
    elect(ctr, xcd, lead);

    for (int i = tid; i < 48 * 128; i += 512) {
        int c = i >> 7, k8 = i & 127;
        *(i32x4*)&sWd[c][k8 * 8] = *(const i32x4*)(Wd + ((size_t)g * 48 + c) * 1024 + k8 * 8);
    }
    if (tid < 48) sB[tid] = bd[g * 48 + tid];
    __syncthreads();

    const int m0 = wave * 16;
    const int rowA = m0 + (lane & 15);
    const int kq = (lane >> 4) * 8;
    const int bcol = lane & 15;
    const int erow = tid >> 2, pair = tid & 3;
    const int hidx2 = erow * 512 + g * 4 + pair;
    float ha = h32[erow * 1024 + g * 8 + pair * 2];
    float hb = h32[erow * 1024 + g * 8 + pair * 2 + 1];

    for (int s = 0; s <= 512; ++s) {
        const __bf16* hcur = (s & 1) ? h1 : h0;
        __bf16* hnxt = (s & 1) ? h0 : h1;
        f32x4 acc0 = {0.f, 0.f, 0.f, 0.f};
        f32x4 acc1 = {0.f, 0.f, 0.f, 0.f};
        f32x4 acc2 = {0.f, 0.f, 0.f, 0.f};
        const __bf16* hr = hcur + (size_t)rowA * 1024;
#pragma unroll 8
        for (int kt = 0; kt < 32; ++kt) {
            bf16x8 a = *(const bf16x8*)(hr + kt * 32 + kq);
            acc0 = __builtin_amdgcn_mfma_f32_16x16x32_bf16(a, *(const bf16x8*)(&sWd[bcol][kt * 32 + kq]), acc0, 0, 0, 0);
            acc1 = __builtin_amdgcn_mfma_f32_16x16x32_bf16(a, *(const bf16x8*)(&sWd[16 + bcol][kt * 32 + kq]), acc1, 0, 0, 0);
            if (has_out)
                acc2 = __builtin_amdgcn_mfma_f32_16x16x32_bf16(a, *(const bf16x8*)(&sWd[32 + bcol][kt * 32 + kq]), acc2, 0, 0, 0);
        }
        int r0 = m0 + ((lane >> 4) << 2);
        if (s < 512) {
#pragma unroll
            for (int i = 0; i < 4; ++i) {
                sG[r0 + i][bcol] = acc0[i];
                sG[r0 + i][16 + bcol] = acc1[i];
            }
        }
        if (has_out) {
#pragma unroll
            for (int i = 0; i < 4; ++i) sG[r0 + i][32 + bcol] = acc2[i];
        }
        __syncthreads();
        // out tile: cols 32..39 = x_s rows (pre-bias); flip to out[:, 512-s, :].
        // Write-through atomic stores: L2 never holds dirty out lines -> inv-safe.
        if (s >= 1 && has_out && tid < 256) {
            int row = tid >> 1, half = tid & 1;
            f2q u;
            u.v = *(const f32x4*)&sG[row][32 + half * 4] + *(const f32x4*)&sB[32 + half * 4];
            u64* dst = (u64*)(out + (size_t)row * 65536 + (size_t)(512 - s) * 128 + g * 8 + half * 4);
            __hip_atomic_store(dst,     u.q[0], __ATOMIC_RELAXED, __HIP_MEMORY_SCOPE_AGENT);
            __hip_atomic_store(dst + 1, u.q[1], __ATOMIC_RELAXED, __HIP_MEMORY_SCOPE_AGENT);
        }
        if (s < 512) {
            f32x4 g0 = *(const f32x4*)&sG[erow][pair * 8];
            f32x4 g1 = *(const f32x4*)&sG[erow][pair * 8 + 4];
            int c0 = pair * 8;
            float r = 1.f / (1.f + __expf(-(g0[0] + sB[c0 + 0])));
            float z = 1.f / (1.f + __expf(-(g0[1] + sB[c0 + 1])));
            float n = tanhf(g0[2] + sB[c0 + 2] + r * (g0[3] + sB[c0 + 3]));
            ha = (1.f - z) * n + z * ha;
            r = 1.f / (1.f + __expf(-(g1[0] + sB[c0 + 4])));
            z = 1.f / (1.f + __expf(-(g1[1] + sB[c0 + 5])));
            n = tanhf(g1[2] + sB[c0 + 6] + r * (g1[3] + sB[c0 + 7]));
            hb = (1.f - z) * n + z * hb;
            pk2 p; p.h[0] = (__bf16)ha; p.h[1] = (__bf16)hb;
            __hip_atomic_store((unsigned*)hnxt + hidx2, p.u, __ATOMIC_RELAXED, __HIP_MEMORY_SCOPE_AGENT);
            __syncthreads();              // drains h + out stores before arrive
            bar_arrive(ctr, g);
            bar_wait(ctr, xcd, lead, (unsigned)(s + 1));
        }
    }
}

// ---------------- launch ----------------
extern "C" void kernel_launch(void* const* d_in, const int* in_sizes, int n_in,
                              void* d_out, int out_size, void* d_ws, size_t ws_size,
                              hipStream_t stream) {
    (void)in_sizes; (void)n_in; (void)out_size; (void)ws_size;
    const float* x    = (const float*)d_in[0];
    const float* Wihe = (const float*)d_in[1];
    const float* Whhe = (const float*)d_in[2];
    const float* bihe = (const float*)d_in[3];
    const float* bhhe = (const float*)d_in[4];
    const float* Wihd = (const float*)d_in[5];
    const float* Whhd = (const float*)d_in[6];
    const float* bihd = (const float*)d_in[7];
    const float* bhhd = (const float*)d_in[8];
    const float* Wout = (const float*)d_in[9];
    const float* bout = (const float*)d_in[10];

    char* ws = (char*)d_ws;
    __bf16*   h0  = (__bf16*)(ws + O_H0);
    __bf16*   h1  = (__bf16*)(ws + O_H1);
    float*    h32 = (float*)(ws + O_H32);
    unsigned* ctr = (unsigned*)(ws + O_CTR);
    __bf16*   xbf = (__bf16*)(ws + O_XB);
    __bf16*   Weh = (__bf16*)(ws + O_WEH);
    __bf16*   Wex = (__bf16*)(ws + O_WEX);
    float*    be  = (float*)(ws + O_BE);
    __bf16*   Wd  = (__bf16*)(ws + O_WD);
    float*    bd  = (float*)(ws + O_BD);
    __bf16*   Wc  = (__bf16*)(ws + O_WC);

    hipMemsetAsync(ws, 0, O_ZERO_END, stream);   // h0/h1/h32 + sync blocks

    k_xcvt<<<4096, 256, 0, stream>>>(x, xbf, B_ * S_ * F_);
    k_pack_enc<<<NWG, 256, 0, stream>>>(Wihe, Whhe, bihe, bhhe, Weh, Wex, be);
    k_wcomb<<<384, 256, 0, stream>>>(Wihd, Wout, Wc);
    k_pack_dec<<<NWG, 256, 0, stream>>>(Whhd, Wc, Wout, Wihd, bihd, bhhd, bout, Wd, bd);

    k_enc<<<NWG, 512, 0, stream>>>(xbf, Weh, Wex, be, h0, h1, h32, ctr);
    k_dec<<<NWG, 512, 0, stream>>>(Wd, bd, h0, h1, h32, (float*)d_out, ctr + 1024);
}